// Round 7
// baseline (358.417 us; speedup 1.0000x reference)
//
#include <hip/hip_runtime.h>
#include <hip/hip_bf16.h>
#include <stdint.h>

typedef __attribute__((ext_vector_type(8))) short short8;
typedef __attribute__((ext_vector_type(4))) short short4v;
typedef __attribute__((ext_vector_type(4))) float f32x4;

__device__ inline unsigned short f2bf(float f) {
    union { float f; uint32_t u; } v; v.f = f;
    uint32_t u = v.u;
    uint32_t r = (u + 0x7FFFu + ((u >> 16) & 1u)) >> 16;   // RNE
    return (unsigned short)r;
}

__device__ inline short8 pk8(float4 a, float4 b) {
    short8 r;
    r[0] = (short)f2bf(a.x); r[1] = (short)f2bf(a.y);
    r[2] = (short)f2bf(a.z); r[3] = (short)f2bf(a.w);
    r[4] = (short)f2bf(b.x); r[5] = (short)f2bf(b.y);
    r[6] = (short)f2bf(b.z); r[7] = (short)f2bf(b.w);
    return r;
}

__device__ inline short8 pk8v(f32x4 a, f32x4 b) {
    short8 r;
    r[0] = (short)f2bf(a[0]); r[1] = (short)f2bf(a[1]);
    r[2] = (short)f2bf(a[2]); r[3] = (short)f2bf(a[3]);
    r[4] = (short)f2bf(b[0]); r[5] = (short)f2bf(b[1]);
    r[6] = (short)f2bf(b[2]); r[7] = (short)f2bf(b[3]);
    return r;
}

// ---------------- Prep: transpose gen_W + 8 experts to k-tiled f32 slabs ------
// srcs[src][kt][n][ksub]: [9][29][512][32] f32 (17.1 MB total, shared across all
// batteries -> L2/L3-resident for moe_gemm). Same T-staging as the old
// combine_w, minus the 64-battery loop. i >= 900 zero-padded.
__global__ __launch_bounds__(256) void prep_src(const float* __restrict__ genW,
                                                const float* __restrict__ expW,
                                                float* __restrict__ srcs) {
    __shared__ float T[9][32 * 36];   // [src][d_loc][i_loc], pad 36
    const int t  = threadIdx.x;
    const int d0 = blockIdx.x * 32;
    const int kt = blockIdx.y;
    const int i0 = kt * 32;
    {
        const int il = t >> 3, d4 = (t & 7) * 4;
        const int i = i0 + il;
        const bool valid = (i < 900);
        const size_t off = (size_t)i * 512 + d0 + d4;
        #pragma unroll
        for (int s = 0; s < 9; ++s) {
            const float* src = (s == 0) ? genW : (expW + (size_t)(s - 1) * 900 * 512);
            float4 v = valid ? *(const float4*)(src + off) : make_float4(0, 0, 0, 0);
            float* Td = &T[s][0];
            Td[(d4 + 0) * 36 + il] = v.x;
            Td[(d4 + 1) * 36 + il] = v.y;
            Td[(d4 + 2) * 36 + il] = v.z;
            Td[(d4 + 3) * 36 + il] = v.w;
        }
    }
    __syncthreads();
    const int dl = t >> 3, sg = t & 7;   // d-row 0..31, i-segment (4 i each)
    float* base = srcs + (size_t)kt * 16384 + (size_t)(d0 + dl) * 32 + sg * 4;
    #pragma unroll
    for (int s = 0; s < 9; ++s)
        *(float4*)(base + (size_t)s * 475136) = *(const float4*)&T[s][dl * 36 + sg * 4];
}

// ---------------- Router kernel 1: partial GEMM  h_pre = g_in @ W1 -------------
// (unchanged from R6) 4 j/thread, software-pipelined W1 loads, k-split 64.
__global__ __launch_bounds__(256) void router1(const float* __restrict__ DKP,
                                               const float* __restrict__ W1,
                                               float* __restrict__ part) {
    __shared__ float gin[16 * 64];   // 4 KB
    const int t  = threadIdx.x;
    const int g  = blockIdx.x;                        // 0..511
    const int jc = g & 1;
    const int bg = (g >> 3) & 3;
    const int ks = ((g >> 1) & 3) | ((g >> 5) << 2);  // 0..63
    const int k0 = ks * 64;
    {   // stage g_in chunk [16 b][64 k]
        const int bl = t >> 4, q = t & 15;
        *(float4*)(gin + bl * 64 + q * 4) =
            *(const float4*)(DKP + (size_t)(bg * 16 + bl) * 4096 + k0 + q * 4);
    }
    __syncthreads();
    const int ja = jc * 1024 + t * 4;   // 4 contiguous j per thread
    f32x4 acc[16];
    #pragma unroll
    for (int bl = 0; bl < 16; ++bl) acc[bl] = (f32x4){0.f, 0.f, 0.f, 0.f};
    f32x4 wcur[8], wnxt[8];
    #pragma unroll
    for (int i = 0; i < 8; ++i)
        wcur[i] = *(const f32x4*)(W1 + (size_t)(k0 + i) * 2048 + ja);
    #pragma unroll 1
    for (int oct = 0; oct < 8; ++oct) {
        const int kk = oct * 8;
        if (oct < 7) {
            #pragma unroll
            for (int i = 0; i < 8; ++i)
                wnxt[i] = *(const f32x4*)(W1 + (size_t)(k0 + kk + 8 + i) * 2048 + ja);
        }
        #pragma unroll
        for (int bl = 0; bl < 16; ++bl) {
            float4 g0 = *(const float4*)(gin + bl * 64 + kk);
            float4 g1 = *(const float4*)(gin + bl * 64 + kk + 4);
            f32x4 a = acc[bl];
            a = a + wcur[0] * g0.x + wcur[1] * g0.y + wcur[2] * g0.z + wcur[3] * g0.w
                  + wcur[4] * g1.x + wcur[5] * g1.y + wcur[6] * g1.z + wcur[7] * g1.w;
            acc[bl] = a;
        }
        #pragma unroll
        for (int i = 0; i < 8; ++i) wcur[i] = wnxt[i];
    }
    #pragma unroll 1
    for (int bl = 0; bl < 16; ++bl)
        *(f32x4*)(part + ((size_t)(ks * 64 + bg * 16 + bl)) * 2048 + ja) = acc[bl];
}

// ---------------- Router 2 (parallel): reduce splits + GELU + partial logits --
// (unchanged from R6)
__global__ __launch_bounds__(256) void router2p(const float* __restrict__ part,
                                                const float* __restrict__ cyc,
                                                const float* __restrict__ W1,
                                                const float* __restrict__ b1,
                                                const float* __restrict__ W2,
                                                float* __restrict__ plog) {
    __shared__ float red[256 * 8];
    const int b = blockIdx.x, jc = blockIdx.y;
    const int t = threadIdx.x;
    const int j = jc * 256 + t;
    float s = 0.f;
    #pragma unroll 8
    for (int tt = 0; tt < 64; ++tt)
        s += part[((size_t)tt * 64 + b) * 2048 + j];
    s += cyc[b] * W1[(size_t)4096 * 2048 + j] + b1[j];
    // jax.nn.gelu default (tanh approximation)
    const float u  = s + 0.044715f * s * s * s;
    const float th = tanhf(0.7978845608028654f * u);
    const float hv = 0.5f * s * (1.0f + th);
    const float* w = W2 + (size_t)j * 8;
    #pragma unroll
    for (int e = 0; e < 8; ++e) red[t * 8 + e] = hv * w[e];
    __syncthreads();
    if (t < 8) {
        float acc = 0.f;
        for (int r = 0; r < 256; ++r) acc += red[r * 8 + t];
        plog[((size_t)b * 8 + jc) * 8 + t] = acc;
    }
}

// ---------------- Main fused GEMM: out[b] = x[b] @ (genW + g0 We0 + g1 We1) ----
// R7: combine_w ELIMINATED. The 296 MB wcomb write+re-read (59 + 4x59) was the
// dominant byte block at the measured ~8.3 B/cy/CU per-CU VMEM rate (invariant
// across R0-R6 pipeline variants — bytes, not latency, is the wall). B-staging
// now loads the 3 relevant f32 source slabs (k-tiled by prep_src; 16.7 MB pool,
// L2/L3-hot) into regs, combines with the SAME f32 fma + RNE-pack arithmetic as
// the old combine_w (absmax-identical), and ds_writes the SAME LDS image that
// global_load_lds produced (linear chunk*512 + lane*8, conflict-free). The
// combine VALU (~240 op/thread/k-step) lands in the idle VALU pipe (8.8% busy).
// Gates (old router4) fused into the prologue: wave 0 shuffle-reduces plog.
// Tiling unchanged from R4/R6: BM=128/BN=512, 8 waves (2m x 4n), BK=32, grid
// 256 = 64 b x 4 m, battery's m-siblings on one XCD.
__global__ __launch_bounds__(512, 1) void moe_gemm(const float* __restrict__ x,
                                                   const float* __restrict__ srcs,
                                                   const float* __restrict__ plog,
                                                   const float* __restrict__ b2,
                                                   const float* __restrict__ eb,
                                                   const float* __restrict__ genb,
                                                   float* __restrict__ out) {
    __shared__ unsigned short As[2][128 * 40];   // [m][k] bf16, stride 40 (20 KB)
    __shared__ unsigned short Bs[2][512 * 32];   // [n][k] bf16, slot-swizzled (64 KB)
    __shared__ float lgsh[8];
    __shared__ float4 gate_sh;
    const int g  = blockIdx.x;                   // 0..255
    const int b  = (g & 7) + 8 * (g >> 5);
    const int m0 = ((g >> 3) & 3) * 128;
    const int t = threadIdx.x, lane = t & 63, wid = t >> 6;

    // ---- gates: wave 0 reduces plog[b][jc][e] over jc, thread 0 does top-2.
    if (wid == 0) {
        const int e = lane & 7, jc = lane >> 3;
        float v = plog[(size_t)b * 64 + jc * 8 + e];
        v += __shfl_xor(v, 8);
        v += __shfl_xor(v, 16);
        v += __shfl_xor(v, 32);
        if (lane < 8) lgsh[e] = v + b2[e];
    }
    __syncthreads();
    if (t == 0) {
        float l[8];
        #pragma unroll
        for (int e = 0; e < 8; ++e) l[e] = lgsh[e];
        int e0 = 0;
        #pragma unroll
        for (int e = 1; e < 8; ++e) if (l[e] > l[e0]) e0 = e;
        int e1 = (e0 == 0) ? 1 : 0;
        #pragma unroll
        for (int e = 0; e < 8; ++e) if (e != e0 && l[e] > l[e1]) e1 = e;
        const float m = l[e0];
        float p[8], Z = 0.f;
        #pragma unroll
        for (int e = 0; e < 8; ++e) { p[e] = expf(l[e] - m); Z += p[e]; }
        const float pe0 = p[e0] / Z, pe1 = p[e1] / Z;
        const float s2 = pe0 + pe1 + 1e-9f;
        gate_sh = make_float4(__int_as_float(e0), __int_as_float(e1), pe0 / s2, pe1 / s2);
    }
    __syncthreads();
    const float4 gt = gate_sh;
    const int e0 = __float_as_int(gt.x), e1 = __float_as_int(gt.y);
    const float g0 = gt.z, g1 = gt.w;

    const float* xb  = x + (size_t)b * 512 * 900;
    const float* sG  = srcs;
    const float* sE0 = srcs + (size_t)(1 + e0) * 475136;
    const float* sE1 = srcs + (size_t)(1 + e1) * 475136;

    f32x4 acc[4][8];
    #pragma unroll
    for (int mi = 0; mi < 4; ++mi)
        #pragma unroll
        for (int ni = 0; ni < 8; ++ni)
            acc[mi][ni] = (f32x4){0.f, 0.f, 0.f, 0.f};

    // A staging: thread -> row t>>2 (128 rows), 8 floats at (t&3)*8
    const int arow = t >> 2;
    const int acol = (t & 3) * 8;
    const float* xrow = xb + (size_t)(m0 + arow) * 900 + acol;
    // B staging: per r, lane covers (n = chunk*16 + lane>>2, global k-seg
    // bseg = (lane&3)^((lane>>3)&3)); LDS write is LINEAR chunk*512 + lane*8 —
    // identical image to the old global_load_lds path (read side unchanged).
    const int bseg = (lane & 3) ^ ((lane >> 3) & 3);
    size_t foffs[4];
    #pragma unroll
    for (int r = 0; r < 4; ++r)
        foffs[r] = (size_t)((wid * 4 + r) * 16 + (lane >> 2)) * 32 + bseg * 8;

    const int wm = wid >> 2;            // 0..1 : m-half
    const int wn = (wid & 3) * 128;     // n-origin of wave
    const int lm = lane & 15, lq = lane >> 4;

    auto loadA = [&](int kt, float4& lo, float4& hi) {
        if (kt < 28) {
            lo = *(const float4*)(xrow + kt * 32);
            hi = *(const float4*)(xrow + kt * 32 + 4);
        } else {   // k = 896+acol..: valid only acol==0 (floats 896..899)
            lo = make_float4(0.f, 0.f, 0.f, 0.f);
            hi = make_float4(0.f, 0.f, 0.f, 0.f);
            if (acol == 0) lo = *(const float4*)(xb + (size_t)(m0 + arow) * 900 + 896);
        }
    };
    auto packA = [&](int buf, float4 lo, float4 hi) {
        *(short8*)&As[buf][arow * 40 + acol] = pk8(lo, hi);
    };
    // combine one r-chunk from registers and write to LDS
    auto commitB = [&](int buf, int r, const f32x4 G[2], const f32x4 EA[2], const f32x4 EB[2]) {
        f32x4 lo = G[0] + g0 * EA[0] + g1 * EB[0];
        f32x4 hi = G[1] + g0 * EA[1] + g1 * EB[1];
        *(short8*)&Bs[buf][(wid * 4 + r) * 512 + lane * 8] = pk8v(lo, hi);
    };
    auto loadSrc = [&](int kt, int r, f32x4 G[2], f32x4 EA[2], f32x4 EB[2]) {
        const size_t fo = foffs[r] + (size_t)kt * 16384;
        G[0]  = *(const f32x4*)(sG + fo);   G[1]  = *(const f32x4*)(sG + fo + 4);
        EA[0] = *(const f32x4*)(sE0 + fo);  EA[1] = *(const f32x4*)(sE0 + fo + 4);
        EB[0] = *(const f32x4*)(sE1 + fo);  EB[1] = *(const f32x4*)(sE1 + fo + 4);
    };
    auto compute = [&](int buf) {
        short8 af[4];
        #pragma unroll
        for (int mi = 0; mi < 4; ++mi)
            af[mi] = *(const short8*)&As[buf][(wm * 64 + mi * 16 + lm) * 40 + lq * 8];
        #pragma unroll
        for (int ni = 0; ni < 8; ++ni) {
            const int n = wn + ni * 16 + lm;
            const int slot = lq ^ ((lm >> 1) & 3);
            short8 bf = *(const short8*)&Bs[buf][n * 32 + slot * 8];
            #pragma unroll
            for (int mi = 0; mi < 4; ++mi)
                acc[mi][ni] = __builtin_amdgcn_mfma_f32_16x16x32_bf16(
                    af[mi], bf, acc[mi][ni], 0, 0, 0);
        }
    };
    // one pipeline step: stage kt_next into bufN while computing bufC.
    // r0,r1 src loads are issued BEFORE compute (latency hides under MFMA);
    // r2,r3 issue after, partially hidden under r0/r1's combine VALU.
    auto step = [&](int bufC, int bufN, int kt_next) {
        float4 aLo, aHi;
        loadA(kt_next, aLo, aHi);
        f32x4 G0[2], EA0[2], EB0[2], G1v[2], EA1[2], EB1[2];
        loadSrc(kt_next, 0, G0, EA0, EB0);
        loadSrc(kt_next, 1, G1v, EA1, EB1);
        compute(bufC);
        commitB(bufN, 0, G0, EA0, EB0);
        commitB(bufN, 1, G1v, EA1, EB1);
        loadSrc(kt_next, 2, G0, EA0, EB0);
        loadSrc(kt_next, 3, G1v, EA1, EB1);
        commitB(bufN, 2, G0, EA0, EB0);
        commitB(bufN, 3, G1v, EA1, EB1);
        packA(bufN, aLo, aHi);
        __syncthreads();
    };

    // ---- prologue: stage kt=0 into buf 0
    {
        float4 aLo, aHi;
        loadA(0, aLo, aHi);
        f32x4 G[2], EA[2], EB[2];
        #pragma unroll
        for (int r = 0; r < 4; ++r) {
            loadSrc(0, r, G, EA, EB);
            commitB(0, r, G, EA, EB);
        }
        packA(0, aLo, aHi);
        __syncthreads();
    }
    // ---- main loop: stage kt 1..28, compute kt 0..27
    #pragma unroll 1
    for (int p = 0; p < 14; ++p) {
        step(0, 1, 2 * p + 1);
        step(1, 0, 2 * p + 2);
    }
    // ---- final: compute kt=28 (in buf 0)
    compute(0);

    // ---- Epilogue: add gen_b + g0*eb[e0] + g1*eb[e1], store f32
    #pragma unroll
    for (int ni = 0; ni < 8; ++ni) {
        const int col = wn + ni * 16 + lm;
        const float bias = genb[col] + g0 * eb[e0 * 512 + col] + g1 * eb[e1 * 512 + col];
        #pragma unroll
        for (int mi = 0; mi < 4; ++mi) {
            const int row = m0 + wm * 64 + mi * 16 + lq * 4;
            #pragma unroll
            for (int r = 0; r < 4; ++r)
                out[((size_t)b * 512 + row + r) * 512 + col] = acc[mi][ni][r] + bias;
        }
    }
}

extern "C" void kernel_launch(void* const* d_in, const int* in_sizes, int n_in,
                              void* d_out, int out_size, void* d_ws, size_t ws_size,
                              hipStream_t stream) {
    const float* x    = (const float*)d_in[0];   // [64][512][900]
    const float* cyc  = (const float*)d_in[1];   // [64][1]
    const float* dkp  = (const float*)d_in[2];   // [64][4096]
    const float* gW1  = (const float*)d_in[3];   // [4097][2048]
    const float* gb1  = (const float*)d_in[4];   // [2048]
    const float* gW2  = (const float*)d_in[5];   // [2048][8]
    const float* gb2  = (const float*)d_in[6];   // [8]
    const float* eW   = (const float*)d_in[7];   // [8][900][512]
    const float* eb   = (const float*)d_in[8];   // [8][512]
    const float* genW = (const float*)d_in[9];   // [900][512]
    const float* genb = (const float*)d_in[10];  // [512]
    float* out = (float*)d_out;                  // [64][512][512] f32

    char* ws = (char*)d_ws;
    // ws layout (no wcomb anymore):
    //   [0, 17104896)                : srcs f32 [9][29][512][32] (k-tiled slabs)
    //   [17104896, 50659328)         : part f32 [64][64][2048]
    //   [50659328, +16KB)            : plog f32 [64][8][8]
    const size_t SRC_BYTES  = 9ull * 29 * 512 * 32 * 4;      // 17,104,896
    const size_t PART_BYTES = 64ull * 64 * 2048 * 4;         // 33,554,432
    float* srcs = (float*)ws;
    float* part = (float*)(ws + SRC_BYTES);
    float* plog = (float*)(ws + SRC_BYTES + PART_BYTES);

    prep_src<<<dim3(16, 29), 256, 0, stream>>>(genW, eW, srcs);
    router1<<<512, 256, 0, stream>>>(dkp, gW1, part);
    router2p<<<dim3(64, 8), 256, 0, stream>>>(part, cyc, gW1, gb1, gW2, plog);
    moe_gemm<<<256, 512, 0, stream>>>(x, srcs, plog, gb2, eb, genb, out);
}